// Round 1
// baseline (343.987 us; speedup 1.0000x reference)
//
#include <hip/hip_runtime.h>
#include <math.h>

// LatentCompressedAttention on MI355X (gfx950), bf16-MFMA pipeline.
// B=2, S=2048, D=2048, H=16, Dh=128, LATENT=512, ROPE=64.

typedef __attribute__((ext_vector_type(8))) short bf16x8;   // 8 bf16 in 4 VGPRs
typedef __attribute__((ext_vector_type(4))) float f32x4;

#define GLDS(gp, lp)                                                         \
  __builtin_amdgcn_global_load_lds(                                          \
      (const __attribute__((address_space(1))) void*)(gp),                   \
      (__attribute__((address_space(3))) void*)(lp), 16, 0, 0)

__device__ __forceinline__ short f2bf(float f) {
  unsigned u = __builtin_bit_cast(unsigned, f);
  u += 0x7fffu + ((u >> 16) & 1u);          // RNE
  return (short)(u >> 16);
}
__device__ __forceinline__ float b2f(short x) {
  unsigned u = ((unsigned)(unsigned short)x) << 16;
  return __builtin_bit_cast(float, u);
}

// ---------------------------------------------------------------- casts ----
__global__ void cast4_kernel(const float* __restrict__ x, short* __restrict__ xb, int n4) {
  int i = blockIdx.x * blockDim.x + threadIdx.x;
  if (i < n4) {
    float4 v = ((const float4*)x)[i];
    ushort4 o;
    o.x = (unsigned short)f2bf(v.x);
    o.y = (unsigned short)f2bf(v.y);
    o.z = (unsigned short)f2bf(v.z);
    o.w = (unsigned short)f2bf(v.w);
    ((ushort4*)xb)[i] = o;
  }
}

// W[K][N] fp32 -> Wt[N][K] bf16 (32x32 LDS tile transpose, both sides coalesced)
__global__ void transpose_cast_kernel(const float* __restrict__ W, short* __restrict__ Wt,
                                      int K, int N) {
  __shared__ float tile[32][33];
  int n0 = blockIdx.x * 32, k0 = blockIdx.y * 32;
  int tx = threadIdx.x & 31, ty = threadIdx.x >> 5;   // ty in 0..7
#pragma unroll
  for (int i = 0; i < 4; ++i)
    tile[ty + i * 8][tx] = W[(size_t)(k0 + ty + i * 8) * N + n0 + tx];
  __syncthreads();
#pragma unroll
  for (int i = 0; i < 4; ++i)
    Wt[(size_t)(n0 + ty + i * 8) * K + k0 + tx] = f2bf(tile[tx][ty + i * 8]);
}

// cos/sin table: [S=2048][32]
__global__ void rope_tab_kernel(const int* __restrict__ pos, float* __restrict__ cosT,
                                float* __restrict__ sinT) {
  int idx = blockIdx.x * 256 + threadIdx.x;
  if (idx < 2048 * 32) {
    int s = idx >> 5, i = idx & 31;
    float p = (float)pos[s];
    float freq = p * powf(10000.0f, -(float)(2 * i) / 64.0f);
    float sv, cv;
    sincosf(freq, &sv, &cv);
    cosT[idx] = cv;
    sinT[idx] = sv;
  }
}

// ----------------------------------------------------------------- GEMM ----
// C[M,N] = A[M,K] @ Bt[N,K]^T, all bf16 in, 128x128 tile, BK=32, 4 waves.
// MODE 0: bf16 row-major out. MODE 1: f32 row-major out.
// MODE 2: bf16 transposed-within-batch out: Vt[(b*2048 + n)*2048 + s], m=b*2048+s.
template <int MODE>
__global__ __launch_bounds__(256, 2) void gemm_bt(const short* __restrict__ A,
                                                  const short* __restrict__ Bt,
                                                  void* __restrict__ Cv,
                                                  int M, int N, int K) {
  __shared__ alignas(16) short sm[16384];   // A bufs: 0,4096 ; B bufs: 8192,12288 (shorts)
  const int tid  = threadIdx.x;
  const int lane = tid & 63;
  const int w    = tid >> 6;
  const int col  = lane & 15, g = lane >> 4;
  const int bm = blockIdx.y * 128, bn = blockIdx.x * 128;
  const int wr = w >> 1, wc = w & 1;

  f32x4 zero4 = {0.f, 0.f, 0.f, 0.f};
  f32x4 acc[4][4];
#pragma unroll
  for (int m = 0; m < 4; ++m)
#pragma unroll
    for (int n = 0; n < 4; ++n) acc[m][n] = zero4;

  const int srow = tid >> 2;            // 0..63
  const int skel = (tid & 3) * 8;       // k-element offset of this lane's 16B chunk
  const short* ag = A + (size_t)(bm + srow) * K + skel;
  const short* bg = Bt + (size_t)(bn + srow) * K + skel;

  auto STAGE = [&](int buf, int t) {
#pragma unroll
    for (int i = 0; i < 2; ++i) {
      GLDS(ag + (size_t)t * 32 + (size_t)i * 64 * K, sm + buf * 4096 + i * 2048 + w * 512);
      GLDS(bg + (size_t)t * 32 + (size_t)i * 64 * K, sm + 8192 + buf * 4096 + i * 2048 + w * 512);
    }
  };

  const int nt = K >> 5;
  STAGE(0, 0);
  __syncthreads();
  int buf = 0;
  for (int t = 0; t < nt; ++t) {
    if (t + 1 < nt) STAGE(buf ^ 1, t + 1);     // async prefetch into other buffer
    const short* As = sm + buf * 4096;
    const short* Bs = sm + 8192 + buf * 4096;
    bf16x8 la[4], lb[4];
#pragma unroll
    for (int m = 0; m < 4; ++m)
      la[m] = *(const bf16x8*)(As + (wr * 64 + m * 16 + col) * 32 + g * 8);
#pragma unroll
    for (int n = 0; n < 4; ++n)
      lb[n] = *(const bf16x8*)(Bs + (wc * 64 + n * 16 + col) * 32 + g * 8);
#pragma unroll
    for (int m = 0; m < 4; ++m)
#pragma unroll
      for (int n = 0; n < 4; ++n)
        acc[m][n] = __builtin_amdgcn_mfma_f32_16x16x32_bf16(la[m], lb[n], acc[m][n], 0, 0, 0);
    __syncthreads();   // drains vmcnt(0)+lgkmcnt before barrier -> staged tile visible
    buf ^= 1;
  }

  const int orow0 = bm + wr * 64;
  const int ocol0 = bn + wc * 64;
  if (MODE == 0) {
    short* C = (short*)Cv;
#pragma unroll
    for (int m = 0; m < 4; ++m)
#pragma unroll
      for (int n = 0; n < 4; ++n)
#pragma unroll
        for (int r = 0; r < 4; ++r)
          C[(size_t)(orow0 + m * 16 + g * 4 + r) * N + ocol0 + n * 16 + col] =
              f2bf(acc[m][n][r]);
  } else if (MODE == 1) {
    float* C = (float*)Cv;
#pragma unroll
    for (int m = 0; m < 4; ++m)
#pragma unroll
      for (int n = 0; n < 4; ++n)
#pragma unroll
        for (int r = 0; r < 4; ++r)
          C[(size_t)(orow0 + m * 16 + g * 4 + r) * N + ocol0 + n * 16 + col] =
              acc[m][n][r];
  } else {
    // Vt[(b*2048 + n)*2048 + s]; 4 acc rows are 4 consecutive s -> one 8B store.
    short* C = (short*)Cv;
#pragma unroll
    for (int m = 0; m < 4; ++m)
#pragma unroll
      for (int n = 0; n < 4; ++n) {
        int grow = orow0 + m * 16 + g * 4;
        int bb = grow >> 11, s = grow & 2047;
        int cn = ocol0 + n * 16 + col;
        ushort4 pk;
        pk.x = (unsigned short)f2bf(acc[m][n][0]);
        pk.y = (unsigned short)f2bf(acc[m][n][1]);
        pk.z = (unsigned short)f2bf(acc[m][n][2]);
        pk.w = (unsigned short)f2bf(acc[m][n][3]);
        *(ushort4*)(C + ((size_t)(bb * 2048 + cn)) * 2048 + s) = pk;
      }
  }
}

// ------------------------------------------------------------ attention ----
// grid (qt=32, bh=32); 4 waves x 16 q-rows; KV tiles of 64, double-buffered,
// XOR-swizzled LDS (byte ^= (row&7)<<4) staged via pre-swizzled global src.
__global__ __launch_bounds__(256, 2) void attn_kernel(
    const short* __restrict__ qb, const short* __restrict__ kb,
    const short* __restrict__ vt, short* __restrict__ ob,
    const float* __restrict__ cosT, const float* __restrict__ sinT) {
  // shorts: K bufs @0,8192 ([64][128]); V bufs @16384,24576 ([128][64]); P @32768+w*1152
  __shared__ alignas(16) short sm[37376];
  const int lane = threadIdx.x & 63, w = threadIdx.x >> 6;
  const int col = lane & 15, g = lane >> 4;
  const int qt = blockIdx.x, bh = blockIdx.y;
  const int b = bh >> 4, h = bh & 15;

  // Q A-fragments (row = lane&15) + in-register RoPE (d and d+32 are lane-local)
  const int qrow = qt * 64 + w * 16 + col;
  const short* qp = qb + ((size_t)(b * 2048 + qrow)) * 2048 + h * 128;
  bf16x8 qf[4];
#pragma unroll
  for (int k4 = 0; k4 < 4; ++k4) qf[k4] = *(const bf16x8*)(qp + k4 * 32 + g * 8);
  {
    const float* cp = cosT + qrow * 32 + g * 8;
    const float* sp = sinT + qrow * 32 + g * 8;
#pragma unroll
    for (int j = 0; j < 8; ++j) {
      float x1 = b2f(qf[0][j]), x2 = b2f(qf[1][j]);
      float c = cp[j], s = sp[j];
      qf[0][j] = f2bf(x1 * c - x2 * s);
      qf[1][j] = f2bf(x1 * s + x2 * c);
    }
  }

  f32x4 zero4 = {0.f, 0.f, 0.f, 0.f};
  f32x4 o[8];
#pragma unroll
  for (int i = 0; i < 8; ++i) o[i] = zero4;
  float mrow[4] = {-3.0e38f, -3.0e38f, -3.0e38f, -3.0e38f};
  float lrow[4] = {0.f, 0.f, 0.f, 0.f};

  auto STAGE = [&](int buf, int kt) {
    // K tile [64 keys][128 d], rows 256B; inverse-swizzle the global source.
#pragma unroll
    for (int i = 0; i < 4; ++i) {
      int r = w * 16 + i * 4 + (lane >> 4);
      int offl = ((lane & 15) * 16) ^ ((r & 7) << 4);
      const short* gp = kb + ((size_t)(b * 2048 + kt * 64 + r)) * 2048 + h * 128 + (offl >> 1);
      GLDS(gp, sm + buf * 8192 + w * 2048 + i * 512);
    }
    // V^T tile [128 d][64 keys], rows 128B.
#pragma unroll
    for (int i = 0; i < 4; ++i) {
      int rd = w * 32 + i * 8 + (lane >> 3);
      int offl = ((lane & 7) * 16) ^ ((rd & 7) << 4);
      const short* gp = vt + ((size_t)(b * 2048 + h * 128 + rd)) * 2048 + kt * 64 + (offl >> 1);
      GLDS(gp, sm + 16384 + buf * 8192 + w * 2048 + i * 512);
    }
  };

  const float scale = 0.08838834764831845f;   // 1/sqrt(128)
  STAGE(0, 0);
  __syncthreads();
  int buf = 0;
  for (int kt = 0; kt < 32; ++kt) {
    if (kt + 1 < 32) STAGE(buf ^ 1, kt + 1);
    const short* Ks = sm + buf * 8192;
    const short* Vs = sm + 16384 + buf * 8192;
    short* Ps = sm + 32768 + w * 1152;          // [16][72] bf16, wave-private

    // QK^T: S[16 q][64 keys]
    f32x4 sa[4];
#pragma unroll
    for (int n = 0; n < 4; ++n) {
      f32x4 a = zero4;
      int kr = n * 16 + col;
#pragma unroll
      for (int k4 = 0; k4 < 4; ++k4) {
        int off = (((g * 16 + k4 * 64) ^ ((kr & 7) << 4)) >> 1) + kr * 128;
        bf16x8 kf = *(const bf16x8*)(Ks + off);
        a = __builtin_amdgcn_mfma_f32_16x16x32_bf16(qf[k4], kf, a, 0, 0, 0);
      }
      sa[n] = a;
    }

    // online softmax (rows g*4+r; 16-lane-group xor reduce over keys)
    float pb[4][4], tmax[4], fr[4], ps[4];
#pragma unroll
    for (int n = 0; n < 4; ++n)
#pragma unroll
      for (int r = 0; r < 4; ++r) pb[n][r] = sa[n][r] * scale;
#pragma unroll
    for (int r = 0; r < 4; ++r)
      tmax[r] = fmaxf(fmaxf(pb[0][r], pb[1][r]), fmaxf(pb[2][r], pb[3][r]));
#pragma unroll
    for (int msk = 1; msk <= 8; msk <<= 1)
#pragma unroll
      for (int r = 0; r < 4; ++r) tmax[r] = fmaxf(tmax[r], __shfl_xor(tmax[r], msk));
#pragma unroll
    for (int r = 0; r < 4; ++r) {
      float mn = fmaxf(mrow[r], tmax[r]);
      fr[r] = __expf(mrow[r] - mn);
      mrow[r] = mn;
      lrow[r] *= fr[r];
      ps[r] = 0.f;
    }
#pragma unroll
    for (int df = 0; df < 8; ++df)
#pragma unroll
      for (int r = 0; r < 4; ++r) o[df][r] *= fr[r];
#pragma unroll
    for (int n = 0; n < 4; ++n)
#pragma unroll
      for (int r = 0; r < 4; ++r) {
        float e = __expf(pb[n][r] - mrow[r]);
        pb[n][r] = e;
        ps[r] += e;
      }
#pragma unroll
    for (int msk = 1; msk <= 8; msk <<= 1)
#pragma unroll
      for (int r = 0; r < 4; ++r) ps[r] += __shfl_xor(ps[r], msk);
#pragma unroll
    for (int r = 0; r < 4; ++r) lrow[r] += ps[r];

    // P (C-layout) -> LDS -> A-layout fragments
#pragma unroll
    for (int n = 0; n < 4; ++n)
#pragma unroll
      for (int r = 0; r < 4; ++r)
        Ps[(g * 4 + r) * 72 + n * 16 + col] = f2bf(pb[n][r]);
    asm volatile("s_waitcnt lgkmcnt(0)" ::: "memory");

    // PV: O[16 q][128 d] += P[16][64] @ V[64][128]
#pragma unroll
    for (int kk = 0; kk < 2; ++kk) {
      bf16x8 pa = *(const bf16x8*)(Ps + col * 72 + kk * 32 + g * 8);
#pragma unroll
      for (int df = 0; df < 8; ++df) {
        int vr = df * 16 + col;
        int off = (((g * 16 + kk * 64) ^ ((vr & 7) << 4)) >> 1) + vr * 64;
        bf16x8 vf = *(const bf16x8*)(Vs + off);
        o[df] = __builtin_amdgcn_mfma_f32_16x16x32_bf16(pa, vf, o[df], 0, 0, 0);
      }
    }
    __syncthreads();
    buf ^= 1;
  }

#pragma unroll
  for (int df = 0; df < 8; ++df)
#pragma unroll
    for (int r = 0; r < 4; ++r) {
      int row = qt * 64 + w * 16 + g * 4 + r;
      int c = h * 128 + df * 16 + col;
      ob[((size_t)(b * 2048 + row)) * 2048 + c] = f2bf(o[df][r] / lrow[r]);
    }
}

// --------------------------------------------------------------- launch ----
extern "C" void kernel_launch(void* const* d_in, const int* in_sizes, int n_in,
                              void* d_out, int out_size, void* d_ws, size_t ws_size,
                              hipStream_t stream) {
  (void)in_sizes; (void)n_in; (void)out_size; (void)ws_size;
  const float* x  = (const float*)d_in[0];
  const int*   pos = (const int*)d_in[1];
  const float* Wq = (const float*)d_in[2];
  const float* Wc = (const float*)d_in[3];
  const float* Wk = (const float*)d_in[4];
  const float* Wv = (const float*)d_in[5];
  const float* Wo = (const float*)d_in[6];

  char* ws = (char*)d_ws;
  short* xb   = (short*)(ws);                 // x bf16            16.78 MB
  short* qb   = (short*)(ws + 16777216);      // q (pre-rope)      16.78 MB
  short* kvb  = (short*)(ws + 33554432);      // latent            4.19 MB
  short* kb   = (short*)(ws + 37748736);      // k                 16.78 MB
  short* vtb  = (short*)(ws + 54525952);      // v transposed      16.78 MB
  short* obuf = (short*)(ws + 71303168);      // attn out          16.78 MB
  short* wqT  = (short*)(ws + 88080384);      // Wq^T              8.39 MB
  short* wcT  = (short*)(ws + 96468992);      // Wc^T              2.10 MB
  short* wkT  = (short*)(ws + 98566144);      // Wk^T              2.10 MB
  short* wvT  = (short*)(ws + 100663296);     // Wv^T              2.10 MB
  short* woT  = (short*)(ws + 102760448);     // Wo^T              8.39 MB
  float* cosT = (float*)(ws + 111149056);     // 0.26 MB
  float* sinT = (float*)(ws + 111411200);     // 0.26 MB

  cast4_kernel<<<8192, 256, 0, stream>>>(x, xb, 2097152);
  transpose_cast_kernel<<<dim3(64, 64), 256, 0, stream>>>(Wq, wqT, 2048, 2048);
  transpose_cast_kernel<<<dim3(16, 64), 256, 0, stream>>>(Wc, wcT, 2048, 512);
  transpose_cast_kernel<<<dim3(64, 16), 256, 0, stream>>>(Wk, wkT, 512, 2048);
  transpose_cast_kernel<<<dim3(64, 16), 256, 0, stream>>>(Wv, wvT, 512, 2048);
  transpose_cast_kernel<<<dim3(64, 64), 256, 0, stream>>>(Wo, woT, 2048, 2048);
  rope_tab_kernel<<<256, 256, 0, stream>>>(pos, cosT, sinT);

  gemm_bt<0><<<dim3(16, 32), 256, 0, stream>>>(xb, wqT, qb, 4096, 2048, 2048);
  gemm_bt<0><<<dim3(4, 32), 256, 0, stream>>>(xb, wcT, kvb, 4096, 512, 2048);
  gemm_bt<0><<<dim3(16, 32), 256, 0, stream>>>(kvb, wkT, kb, 4096, 2048, 512);
  gemm_bt<2><<<dim3(16, 32), 256, 0, stream>>>(kvb, wvT, vtb, 4096, 2048, 512);

  attn_kernel<<<dim3(32, 32), 256, 0, stream>>>(qb, kb, vtb, obuf, cosT, sinT);

  gemm_bt<1><<<dim3(16, 32), 256, 0, stream>>>(obuf, woT, (float*)d_out, 4096, 2048, 2048);
}

// Round 4
// 285.773 us; speedup vs baseline: 1.2037x; 1.2037x over previous
//
#include <hip/hip_runtime.h>
#include <math.h>

// LatentCompressedAttention on MI355X (gfx950), bf16-MFMA pipeline.
// B=2, S=2048, D=2048, H=16, Dh=128, LATENT=512, ROPE=64.

typedef __attribute__((ext_vector_type(8))) short bf16x8;    // 8 bf16 in 4 VGPRs
typedef __attribute__((ext_vector_type(4))) float f32x4;
typedef __attribute__((ext_vector_type(16))) float f32x16;

#define GLDS(gp, lp)                                                         \
  __builtin_amdgcn_global_load_lds(                                          \
      (const __attribute__((address_space(1))) void*)(gp),                   \
      (__attribute__((address_space(3))) void*)(lp), 16, 0, 0)

__device__ __forceinline__ short f2bf(float f) {
  unsigned u = __builtin_bit_cast(unsigned, f);
  u += 0x7fffu + ((u >> 16) & 1u);          // RNE
  return (short)(u >> 16);
}
__device__ __forceinline__ float b2f(short x) {
  unsigned u = ((unsigned)(unsigned short)x) << 16;
  return __builtin_bit_cast(float, u);
}
// pack two f32 -> dword of 2 bf16 (lo in low short), explicit RNE
__device__ __forceinline__ unsigned pk2(float lo, float hi) {
  return ((unsigned)(unsigned short)f2bf(hi) << 16) |
         (unsigned)(unsigned short)f2bf(lo);
}

// ---------------------------------------------------------------- casts ----
__global__ void cast4_kernel(const float* __restrict__ x, short* __restrict__ xb, int n4) {
  int i = blockIdx.x * blockDim.x + threadIdx.x;
  if (i < n4) {
    float4 v = ((const float4*)x)[i];
    ushort4 o;
    o.x = (unsigned short)f2bf(v.x);
    o.y = (unsigned short)f2bf(v.y);
    o.z = (unsigned short)f2bf(v.z);
    o.w = (unsigned short)f2bf(v.w);
    ((ushort4*)xb)[i] = o;
  }
}

// W[K][N] fp32 -> Wt[N][K] bf16 (32x32 LDS tile transpose, both sides coalesced)
__global__ void transpose_cast_kernel(const float* __restrict__ W, short* __restrict__ Wt,
                                      int K, int N) {
  __shared__ float tile[32][33];
  int n0 = blockIdx.x * 32, k0 = blockIdx.y * 32;
  int tx = threadIdx.x & 31, ty = threadIdx.x >> 5;   // ty in 0..7
#pragma unroll
  for (int i = 0; i < 4; ++i)
    tile[ty + i * 8][tx] = W[(size_t)(k0 + ty + i * 8) * N + n0 + tx];
  __syncthreads();
#pragma unroll
  for (int i = 0; i < 4; ++i)
    Wt[(size_t)(n0 + ty + i * 8) * K + k0 + tx] = f2bf(tile[tx][ty + i * 8]);
}

// cos/sin table: [S=2048][32]
__global__ void rope_tab_kernel(const int* __restrict__ pos, float* __restrict__ cosT,
                                float* __restrict__ sinT) {
  int idx = blockIdx.x * 256 + threadIdx.x;
  if (idx < 2048 * 32) {
    int s = idx >> 5, i = idx & 31;
    float p = (float)pos[s];
    float freq = p * powf(10000.0f, -(float)(2 * i) / 64.0f);
    float sv, cv;
    sincosf(freq, &sv, &cv);
    cosT[idx] = cv;
    sinT[idx] = sv;
  }
}

// ----------------------------------------------------------------- GEMM ----
// C[M,N] = A[M,K] @ Bt[N,K]^T, all bf16 in, 128x128 tile, BK=32, 4 waves.
// MODE 0: bf16 row-major out. MODE 1: f32 row-major out.
// MODE 2: bf16 transposed-within-batch out: Vt[(b*2048 + n)*2048 + s], m=b*2048+s.
template <int MODE>
__global__ __launch_bounds__(256, 2) void gemm_bt(const short* __restrict__ A,
                                                  const short* __restrict__ Bt,
                                                  void* __restrict__ Cv,
                                                  int M, int N, int K) {
  __shared__ alignas(16) short sm[16384];   // A bufs: 0,4096 ; B bufs: 8192,12288 (shorts)
  const int tid  = threadIdx.x;
  const int lane = tid & 63;
  const int w    = tid >> 6;
  const int col  = lane & 15, g = lane >> 4;
  const int bm = blockIdx.y * 128, bn = blockIdx.x * 128;
  const int wr = w >> 1, wc = w & 1;

  f32x4 zero4 = {0.f, 0.f, 0.f, 0.f};
  f32x4 acc[4][4];
#pragma unroll
  for (int m = 0; m < 4; ++m)
#pragma unroll
    for (int n = 0; n < 4; ++n) acc[m][n] = zero4;

  const int srow = tid >> 2;            // 0..63
  const int skel = (tid & 3) * 8;       // k-element offset of this lane's 16B chunk
  const short* ag = A + (size_t)(bm + srow) * K + skel;
  const short* bg = Bt + (size_t)(bn + srow) * K + skel;

  auto STAGE = [&](int buf, int t) {
#pragma unroll
    for (int i = 0; i < 2; ++i) {
      GLDS(ag + (size_t)t * 32 + (size_t)i * 64 * K, sm + buf * 4096 + i * 2048 + w * 512);
      GLDS(bg + (size_t)t * 32 + (size_t)i * 64 * K, sm + 8192 + buf * 4096 + i * 2048 + w * 512);
    }
  };

  const int nt = K >> 5;
  STAGE(0, 0);
  __syncthreads();
  int buf = 0;
  for (int t = 0; t < nt; ++t) {
    if (t + 1 < nt) STAGE(buf ^ 1, t + 1);     // async prefetch into other buffer
    const short* As = sm + buf * 4096;
    const short* Bs = sm + 8192 + buf * 4096;
    bf16x8 la[4], lb[4];
#pragma unroll
    for (int m = 0; m < 4; ++m)
      la[m] = *(const bf16x8*)(As + (wr * 64 + m * 16 + col) * 32 + g * 8);
#pragma unroll
    for (int n = 0; n < 4; ++n)
      lb[n] = *(const bf16x8*)(Bs + (wc * 64 + n * 16 + col) * 32 + g * 8);
#pragma unroll
    for (int m = 0; m < 4; ++m)
#pragma unroll
      for (int n = 0; n < 4; ++n)
        acc[m][n] = __builtin_amdgcn_mfma_f32_16x16x32_bf16(la[m], lb[n], acc[m][n], 0, 0, 0);
    __syncthreads();   // drains vmcnt(0)+lgkmcnt before barrier -> staged tile visible
    buf ^= 1;
  }

  const int orow0 = bm + wr * 64;
  const int ocol0 = bn + wc * 64;
  if (MODE == 0) {
    short* C = (short*)Cv;
#pragma unroll
    for (int m = 0; m < 4; ++m)
#pragma unroll
      for (int n = 0; n < 4; ++n)
#pragma unroll
        for (int r = 0; r < 4; ++r)
          C[(size_t)(orow0 + m * 16 + g * 4 + r) * N + ocol0 + n * 16 + col] =
              f2bf(acc[m][n][r]);
  } else if (MODE == 1) {
    float* C = (float*)Cv;
#pragma unroll
    for (int m = 0; m < 4; ++m)
#pragma unroll
      for (int n = 0; n < 4; ++n)
#pragma unroll
        for (int r = 0; r < 4; ++r)
          C[(size_t)(orow0 + m * 16 + g * 4 + r) * N + ocol0 + n * 16 + col] =
              acc[m][n][r];
  } else {
    // Vt[(b*2048 + n)*2048 + s]; 4 acc rows are 4 consecutive s -> one 8B store.
    short* C = (short*)Cv;
#pragma unroll
    for (int m = 0; m < 4; ++m)
#pragma unroll
      for (int n = 0; n < 4; ++n) {
        int grow = orow0 + m * 16 + g * 4;
        int bb = grow >> 11, s = grow & 2047;
        int cn = ocol0 + n * 16 + col;
        ushort4 pk;
        pk.x = (unsigned short)f2bf(acc[m][n][0]);
        pk.y = (unsigned short)f2bf(acc[m][n][1]);
        pk.z = (unsigned short)f2bf(acc[m][n][2]);
        pk.w = (unsigned short)f2bf(acc[m][n][3]);
        *(ushort4*)(C + ((size_t)(bb * 2048 + cn)) * 2048 + s) = pk;
      }
  }
}

// ------------------------------------------------------------ attention ----
// Swapped-operand 32x32 structure:
//   S^T = K @ Q^T  (mfma A=K, B=Q^T)  -> lane owns one q-column, keys in regs
//   O^T = V^T @ P^T (mfma A=V^T, B=P^T) -> O columns = q, rescale lane-local
// 4 waves x 32 q-rows; KV tiles of 64, double-buffered XOR-swizzled LDS.
// Cross-half exchange via __shfl_xor(.,32) + hi-select ONLY (permlane32_swap
// removed -- its half/output-order semantics were the R2/R3 failure suspect).
__global__ __launch_bounds__(256, 2) void attn_kernel(
    const short* __restrict__ qb, const short* __restrict__ kb,
    const short* __restrict__ vt, short* __restrict__ ob,
    const float* __restrict__ cosT, const float* __restrict__ sinT) {
  // shorts: K bufs @0,8192 ([64 keys][128 d]); V bufs @16384,24576 ([128 d][64 keys])
  __shared__ alignas(16) short sm[32768];
  const int lane = threadIdx.x & 63, w = threadIdx.x >> 6;
  const int ql = lane & 31, hi = lane >> 5;
  const int qt = blockIdx.x, bh = blockIdx.y;
  const int b = bh >> 4, h = bh & 15;
  const int q0w = qt * 128 + w * 32;
  const int qrow = q0w + ql;

  // ---- Q load (B-fragment layout: lane q=ql, d = db*16 + hi*8 + j) + RoPE
  bf16x8 qf[8];
  {
    const short* qp = qb + ((size_t)(b * 2048 + qrow)) * 2048 + h * 128;
#pragma unroll
    for (int db = 0; db < 8; ++db) qf[db] = *(const bf16x8*)(qp + db * 16 + hi * 8);
    const float* cp = cosT + qrow * 32;
    const float* sp = sinT + qrow * 32;
#pragma unroll
    for (int db = 0; db < 2; ++db)
#pragma unroll
      for (int j = 0; j < 8; ++j) {
        int i = db * 16 + hi * 8 + j;
        float x1 = b2f(qf[db][j]), x2 = b2f(qf[db + 2][j]);
        float cv = cp[i], sv = sp[i];
        qf[db][j]     = f2bf(x1 * cv - x2 * sv);
        qf[db + 2][j] = f2bf(x1 * sv + x2 * cv);
      }
  }

  f32x16 o[4];
#pragma unroll
  for (int m4 = 0; m4 < 4; ++m4)
#pragma unroll
    for (int r = 0; r < 16; ++r) o[m4][r] = 0.f;
  float mrun = -3.0e38f, lrun = 0.f;

  auto STAGE = [&](int buf, int kt) {
    // K tile [64 keys][128 d]: linear LDS dest, inverse-swizzled global src.
#pragma unroll
    for (int i = 0; i < 4; ++i) {
      int r = w * 16 + i * 4 + (lane >> 4);
      int cch = lane & 15;
      const short* gp = kb + ((size_t)(b * 2048 + kt * 64 + r)) * 2048 + h * 128 +
                        ((cch ^ (r & 7)) << 3);
      GLDS(gp, sm + buf * 8192 + w * 2048 + i * 512);
    }
    // V^T tile [128 d][64 keys]
#pragma unroll
    for (int i = 0; i < 4; ++i) {
      int rd = w * 32 + i * 8 + (lane >> 3);
      int cch = lane & 7;
      const short* gp = vt + ((size_t)(b * 2048 + h * 128 + rd)) * 2048 + kt * 64 +
                        ((cch ^ (rd & 7)) << 3);
      GLDS(gp, sm + 16384 + buf * 8192 + w * 2048 + i * 512);
    }
  };

  const float scale = 0.08838834764831845f;   // 1/sqrt(128)
  STAGE(0, 0);
  __syncthreads();
  int buf = 0;
  for (int kt = 0; kt < 32; ++kt) {
    if (kt + 1 < 32) STAGE(buf ^ 1, kt + 1);
    const short* Ks = sm + buf * 8192;
    const short* Vs = sm + 16384 + buf * 8192;

    // ---- QK^T (swapped): skt[kb2] = S^T[key block kb2][q], keys in regs
    f32x16 skt[2];
    __builtin_amdgcn_s_setprio(1);
#pragma unroll
    for (int kb2 = 0; kb2 < 2; ++kb2) {
      f32x16 a;
#pragma unroll
      for (int r = 0; r < 16; ++r) a[r] = 0.f;
      int krow = kb2 * 32 + ql;
#pragma unroll
      for (int db = 0; db < 8; ++db) {
        bf16x8 kf = *(const bf16x8*)(Ks + krow * 128 + (((db * 2 + hi) ^ (krow & 7)) << 3));
        a = __builtin_amdgcn_mfma_f32_32x32x16_bf16(kf, qf[db], a, 0, 0, 0);
      }
      skt[kb2] = a;
    }
    __builtin_amdgcn_s_setprio(0);

    // ---- scale in f32
#pragma unroll
    for (int kb2 = 0; kb2 < 2; ++kb2)
#pragma unroll
      for (int r = 0; r < 16; ++r) skt[kb2][r] *= scale;

    // ---- online softmax, lane-local; cross-half combine via shfl_xor(32)
    float t0 = skt[0][0], t1 = skt[0][1], t2 = skt[0][2], t3 = skt[0][3];
#pragma unroll
    for (int r = 4; r < 16; r += 4) {
      t0 = fmaxf(t0, skt[0][r]);     t1 = fmaxf(t1, skt[0][r + 1]);
      t2 = fmaxf(t2, skt[0][r + 2]); t3 = fmaxf(t3, skt[0][r + 3]);
    }
#pragma unroll
    for (int r = 0; r < 16; r += 4) {
      t0 = fmaxf(t0, skt[1][r]);     t1 = fmaxf(t1, skt[1][r + 1]);
      t2 = fmaxf(t2, skt[1][r + 2]); t3 = fmaxf(t3, skt[1][r + 3]);
    }
    float tmax = fmaxf(fmaxf(t0, t1), fmaxf(t2, t3));
    tmax = fmaxf(tmax, __shfl_xor(tmax, 32));
    // true running max every tile
    {
      float mn = fmaxf(mrun, tmax);
      float fr = __expf(mrun - mn);
      mrun = mn;
      lrun *= fr;
#pragma unroll
      for (int m4 = 0; m4 < 4; ++m4)
#pragma unroll
        for (int r = 0; r < 16; ++r) o[m4][r] *= fr;
    }
    // exp in place + row-sum
    float s0 = 0.f, s1 = 0.f, s2 = 0.f, s3 = 0.f;
#pragma unroll
    for (int kb2 = 0; kb2 < 2; ++kb2)
#pragma unroll
      for (int r = 0; r < 16; r += 4) {
        skt[kb2][r]     = __expf(skt[kb2][r] - mrun);
        skt[kb2][r + 1] = __expf(skt[kb2][r + 1] - mrun);
        skt[kb2][r + 2] = __expf(skt[kb2][r + 2] - mrun);
        skt[kb2][r + 3] = __expf(skt[kb2][r + 3] - mrun);
        s0 += skt[kb2][r];     s1 += skt[kb2][r + 1];
        s2 += skt[kb2][r + 2]; s3 += skt[kb2][r + 3];
      }
    float psum = (s0 + s1) + (s2 + s3);
    psum += __shfl_xor(psum, 32);
    lrun += psum;

    // ---- P -> bf16 P^T B-fragments.
    // Lane (ql,hi) holds P[ql][kb2*32 + (r&3)+8*(r>>2)+4*hi].  Target frag
    // pf[ks=2*kb2+half] element (hi,j) = P[ql][key = 32*kb2+16*half+8*hi+j].
    // slot0=[hi0: self a0 | hi1: partner b0], slot1=[a1|pb1],
    // slot2=[hi0: partner a0 | hi1: self b0], slot3=[pa1|b1].
    bf16x8 pf[4];
#pragma unroll
    for (int kb2 = 0; kb2 < 2; ++kb2) {
#pragma unroll
      for (int half = 0; half < 2; ++half) {
        unsigned a0 = pk2(skt[kb2][half * 8 + 0], skt[kb2][half * 8 + 1]);
        unsigned a1 = pk2(skt[kb2][half * 8 + 2], skt[kb2][half * 8 + 3]);
        unsigned b0 = pk2(skt[kb2][half * 8 + 4], skt[kb2][half * 8 + 5]);
        unsigned b1 = pk2(skt[kb2][half * 8 + 6], skt[kb2][half * 8 + 7]);
        unsigned pa0 = __shfl_xor(a0, 32), pa1 = __shfl_xor(a1, 32);
        unsigned pb0 = __shfl_xor(b0, 32), pb1 = __shfl_xor(b1, 32);
        union { unsigned u[4]; bf16x8 v; } tmp;
        tmp.u[0] = hi ? pb0 : a0;
        tmp.u[1] = hi ? pb1 : a1;
        tmp.u[2] = hi ? b0 : pa0;
        tmp.u[3] = hi ? b1 : pa1;
        pf[kb2 * 2 + half] = tmp.v;
      }
    }

    // ---- PV (swapped): O^T[d][q] += V^T @ P^T
    __builtin_amdgcn_s_setprio(1);
#pragma unroll
    for (int m4 = 0; m4 < 4; ++m4) {
      int rd = m4 * 32 + ql;
#pragma unroll
      for (int ks = 0; ks < 4; ++ks) {
        bf16x8 vf = *(const bf16x8*)(Vs + rd * 64 + (((ks * 2 + hi) ^ (rd & 7)) << 3));
        o[m4] = __builtin_amdgcn_mfma_f32_32x32x16_bf16(vf, pf[ks], o[m4], 0, 0, 0);
      }
    }
    __builtin_amdgcn_s_setprio(0);
    __syncthreads();
    buf ^= 1;
  }

  // ---- epilogue: O^T -> LDS transpose (padded rows) -> coalesced bf16 store
  float il = 1.0f / lrun;
  short* E = sm + w * 4352;                    // [32 q][136 shorts], 16B-aligned rows
#pragma unroll
  for (int m4 = 0; m4 < 4; ++m4)
#pragma unroll
    for (int r = 0; r < 16; r += 2) {
      int d = m4 * 32 + (r & 3) + 8 * (r >> 2) + 4 * hi;
      unsigned pk = pk2(o[m4][r] * il, o[m4][r + 1] * il);
      *(unsigned*)(E + ql * 136 + d) = pk;
    }
  asm volatile("s_waitcnt lgkmcnt(0)" ::: "memory");   // wave-private region
#pragma unroll
  for (int it = 0; it < 8; ++it) {
    int row = it * 4 + (lane >> 4);
    int ch = lane & 15;
    bf16x8 v = *(const bf16x8*)(E + row * 136 + ch * 8);
    *(bf16x8*)(ob + ((size_t)(b * 2048 + q0w + row)) * 2048 + h * 128 + ch * 8) = v;
  }
}

// --------------------------------------------------------------- launch ----
extern "C" void kernel_launch(void* const* d_in, const int* in_sizes, int n_in,
                              void* d_out, int out_size, void* d_ws, size_t ws_size,
                              hipStream_t stream) {
  (void)in_sizes; (void)n_in; (void)out_size; (void)ws_size;
  const float* x  = (const float*)d_in[0];
  const int*   pos = (const int*)d_in[1];
  const float* Wq = (const float*)d_in[2];
  const float* Wc = (const float*)d_in[3];
  const float* Wk = (const float*)d_in[4];
  const float* Wv = (const float*)d_in[5];
  const float* Wo = (const float*)d_in[6];

  char* ws = (char*)d_ws;
  short* xb   = (short*)(ws);                 // x bf16            16.78 MB
  short* qb   = (short*)(ws + 16777216);      // q (pre-rope)      16.78 MB
  short* kvb  = (short*)(ws + 33554432);      // latent            4.19 MB
  short* kb   = (short*)(ws + 37748736);      // k                 16.78 MB
  short* vtb  = (short*)(ws + 54525952);      // v transposed      16.78 MB
  short* obuf = (short*)(ws + 71303168);      // attn out          16.78 MB
  short* wqT  = (short*)(ws + 88080384);      // Wq^T              8.39 MB
  short* wcT  = (short*)(ws + 96468992);      // Wc^T              2.10 MB
  short* wkT  = (short*)(ws + 98566144);      // Wk^T              2.10 MB
  short* wvT  = (short*)(ws + 100663296);     // Wv^T              2.10 MB
  short* woT  = (short*)(ws + 102760448);     // Wo^T              8.39 MB
  float* cosT = (float*)(ws + 111149056);     // 0.26 MB
  float* sinT = (float*)(ws + 111411200);     // 0.26 MB

  cast4_kernel<<<8192, 256, 0, stream>>>(x, xb, 2097152);
  transpose_cast_kernel<<<dim3(64, 64), 256, 0, stream>>>(Wq, wqT, 2048, 2048);
  transpose_cast_kernel<<<dim3(16, 64), 256, 0, stream>>>(Wc, wcT, 2048, 512);
  transpose_cast_kernel<<<dim3(64, 16), 256, 0, stream>>>(Wk, wkT, 512, 2048);
  transpose_cast_kernel<<<dim3(64, 16), 256, 0, stream>>>(Wv, wvT, 512, 2048);
  transpose_cast_kernel<<<dim3(64, 64), 256, 0, stream>>>(Wo, woT, 2048, 2048);
  rope_tab_kernel<<<256, 256, 0, stream>>>(pos, cosT, sinT);

  gemm_bt<0><<<dim3(16, 32), 256, 0, stream>>>(xb, wqT, qb, 4096, 2048, 2048);
  gemm_bt<0><<<dim3(4, 32), 256, 0, stream>>>(xb, wcT, kvb, 4096, 512, 2048);
  gemm_bt<0><<<dim3(16, 32), 256, 0, stream>>>(kvb, wkT, kb, 4096, 2048, 512);
  gemm_bt<2><<<dim3(16, 32), 256, 0, stream>>>(kvb, wvT, vtb, 4096, 2048, 512);

  attn_kernel<<<dim3(16, 32), 256, 0, stream>>>(qb, kb, vtb, obuf, cosT, sinT);

  gemm_bt<1><<<dim3(16, 32), 256, 0, stream>>>(obuf, woT, (float*)d_out, 4096, 2048, 2048);
}

// Round 5
// 271.979 us; speedup vs baseline: 1.2648x; 1.0507x over previous
//
#include <hip/hip_runtime.h>
#include <math.h>

// LatentCompressedAttention on MI355X (gfx950), bf16-MFMA pipeline.
// B=2, S=2048, D=2048, H=16, Dh=128, LATENT=512, ROPE=64.

typedef __attribute__((ext_vector_type(8))) short bf16x8;    // 8 bf16 in 4 VGPRs
typedef __attribute__((ext_vector_type(4))) float f32x4;
typedef __attribute__((ext_vector_type(16))) float f32x16;

#define GLDS(gp, lp)                                                         \
  __builtin_amdgcn_global_load_lds(                                          \
      (const __attribute__((address_space(1))) void*)(gp),                   \
      (__attribute__((address_space(3))) void*)(lp), 16, 0, 0)

__device__ __forceinline__ short f2bf(float f) {
  unsigned u = __builtin_bit_cast(unsigned, f);
  u += 0x7fffu + ((u >> 16) & 1u);          // RNE
  return (short)(u >> 16);
}
__device__ __forceinline__ float b2f(short x) {
  unsigned u = ((unsigned)(unsigned short)x) << 16;
  return __builtin_bit_cast(float, u);
}
// HW packed f32->bf16 (v_cvt_pk_bf16_f32; lo in low short)
__device__ __forceinline__ unsigned cvtpk(float lo, float hi) {
  unsigned r;
  asm("v_cvt_pk_bf16_f32 %0, %1, %2" : "=v"(r) : "v"(lo), "v"(hi));
  return r;
}

// ---------------------------------------------------------------- casts ----
__global__ void cast4_kernel(const float* __restrict__ x, short* __restrict__ xb, int n4) {
  int i = blockIdx.x * blockDim.x + threadIdx.x;
  if (i < n4) {
    float4 v = ((const float4*)x)[i];
    ushort4 o;
    o.x = (unsigned short)f2bf(v.x);
    o.y = (unsigned short)f2bf(v.y);
    o.z = (unsigned short)f2bf(v.z);
    o.w = (unsigned short)f2bf(v.w);
    ((ushort4*)xb)[i] = o;
  }
}

// W[K][N] fp32 -> Wt[N][K] bf16 (32x32 LDS tile transpose, both sides coalesced)
__global__ void transpose_cast_kernel(const float* __restrict__ W, short* __restrict__ Wt,
                                      int K, int N) {
  __shared__ float tile[32][33];
  int n0 = blockIdx.x * 32, k0 = blockIdx.y * 32;
  int tx = threadIdx.x & 31, ty = threadIdx.x >> 5;   // ty in 0..7
#pragma unroll
  for (int i = 0; i < 4; ++i)
    tile[ty + i * 8][tx] = W[(size_t)(k0 + ty + i * 8) * N + n0 + tx];
  __syncthreads();
#pragma unroll
  for (int i = 0; i < 4; ++i)
    Wt[(size_t)(n0 + ty + i * 8) * K + k0 + tx] = f2bf(tile[tx][ty + i * 8]);
}

// cos/sin table: [S=2048][32]
__global__ void rope_tab_kernel(const int* __restrict__ pos, float* __restrict__ cosT,
                                float* __restrict__ sinT) {
  int idx = blockIdx.x * 256 + threadIdx.x;
  if (idx < 2048 * 32) {
    int s = idx >> 5, i = idx & 31;
    float p = (float)pos[s];
    float freq = p * powf(10000.0f, -(float)(2 * i) / 64.0f);
    float sv, cv;
    sincosf(freq, &sv, &cv);
    cosT[idx] = cv;
    sinT[idx] = sv;
  }
}

// ----------------------------------------------------------------- GEMM ----
// C[M,N] = A[M,K] @ Bt[N,K]^T, all bf16 in, 128x128 tile, BK=32, 4 waves.
// MODE 0: bf16 row-major out. MODE 1: f32 row-major out.
// MODE 2: bf16 transposed-within-batch out: Vt[(b*2048 + n)*2048 + s], m=b*2048+s.
template <int MODE>
__global__ __launch_bounds__(256, 2) void gemm_bt(const short* __restrict__ A,
                                                  const short* __restrict__ Bt,
                                                  void* __restrict__ Cv,
                                                  int M, int N, int K) {
  __shared__ alignas(16) short sm[16384];   // A bufs: 0,4096 ; B bufs: 8192,12288 (shorts)
  const int tid  = threadIdx.x;
  const int lane = tid & 63;
  const int w    = tid >> 6;
  const int col  = lane & 15, g = lane >> 4;
  const int bm = blockIdx.y * 128, bn = blockIdx.x * 128;
  const int wr = w >> 1, wc = w & 1;

  f32x4 zero4 = {0.f, 0.f, 0.f, 0.f};
  f32x4 acc[4][4];
#pragma unroll
  for (int m = 0; m < 4; ++m)
#pragma unroll
    for (int n = 0; n < 4; ++n) acc[m][n] = zero4;

  const int srow = tid >> 2;            // 0..63
  const int skel = (tid & 3) * 8;       // k-element offset of this lane's 16B chunk
  const short* ag = A + (size_t)(bm + srow) * K + skel;
  const short* bg = Bt + (size_t)(bn + srow) * K + skel;

  auto STAGE = [&](int buf, int t) {
#pragma unroll
    for (int i = 0; i < 2; ++i) {
      GLDS(ag + (size_t)t * 32 + (size_t)i * 64 * K, sm + buf * 4096 + i * 2048 + w * 512);
      GLDS(bg + (size_t)t * 32 + (size_t)i * 64 * K, sm + 8192 + buf * 4096 + i * 2048 + w * 512);
    }
  };

  const int nt = K >> 5;
  STAGE(0, 0);
  __syncthreads();
  int buf = 0;
  for (int t = 0; t < nt; ++t) {
    if (t + 1 < nt) STAGE(buf ^ 1, t + 1);     // async prefetch into other buffer
    const short* As = sm + buf * 4096;
    const short* Bs = sm + 8192 + buf * 4096;
    bf16x8 la[4], lb[4];
#pragma unroll
    for (int m = 0; m < 4; ++m)
      la[m] = *(const bf16x8*)(As + (wr * 64 + m * 16 + col) * 32 + g * 8);
#pragma unroll
    for (int n = 0; n < 4; ++n)
      lb[n] = *(const bf16x8*)(Bs + (wc * 64 + n * 16 + col) * 32 + g * 8);
#pragma unroll
    for (int m = 0; m < 4; ++m)
#pragma unroll
      for (int n = 0; n < 4; ++n)
        acc[m][n] = __builtin_amdgcn_mfma_f32_16x16x32_bf16(la[m], lb[n], acc[m][n], 0, 0, 0);
    __syncthreads();   // drains vmcnt(0)+lgkmcnt before barrier -> staged tile visible
    buf ^= 1;
  }

  const int orow0 = bm + wr * 64;
  const int ocol0 = bn + wc * 64;
  if (MODE == 0) {
    short* C = (short*)Cv;
#pragma unroll
    for (int m = 0; m < 4; ++m)
#pragma unroll
      for (int n = 0; n < 4; ++n)
#pragma unroll
        for (int r = 0; r < 4; ++r)
          C[(size_t)(orow0 + m * 16 + g * 4 + r) * N + ocol0 + n * 16 + col] =
              f2bf(acc[m][n][r]);
  } else if (MODE == 1) {
    float* C = (float*)Cv;
#pragma unroll
    for (int m = 0; m < 4; ++m)
#pragma unroll
      for (int n = 0; n < 4; ++n)
#pragma unroll
        for (int r = 0; r < 4; ++r)
          C[(size_t)(orow0 + m * 16 + g * 4 + r) * N + ocol0 + n * 16 + col] =
              acc[m][n][r];
  } else {
    // Vt[(b*2048 + n)*2048 + s]; 4 acc rows are 4 consecutive s -> one 8B store.
    short* C = (short*)Cv;
#pragma unroll
    for (int m = 0; m < 4; ++m)
#pragma unroll
      for (int n = 0; n < 4; ++n) {
        int grow = orow0 + m * 16 + g * 4;
        int bb = grow >> 11, s = grow & 2047;
        int cn = ocol0 + n * 16 + col;
        ushort4 pk;
        pk.x = (unsigned short)f2bf(acc[m][n][0]);
        pk.y = (unsigned short)f2bf(acc[m][n][1]);
        pk.z = (unsigned short)f2bf(acc[m][n][2]);
        pk.w = (unsigned short)f2bf(acc[m][n][3]);
        *(ushort4*)(C + ((size_t)(bb * 2048 + cn)) * 2048 + s) = pk;
      }
  }
}

// ------------------------------------------------------------ attention ----
// Swapped-operand 32x32 structure (R4-verified data path):
//   S^T = K @ Q^T ; O^T = V^T @ P^T ; lane owns one q-row's softmax state.
// This round: XCD-locality 1D grid (bid%8 = bh%8 -> 4 heads' K/V per L2),
// log2-domain softmax (scale*log2e fold + exp2), defer-max THR=8,
// cvt_pk packing, max3 reduce tree.  pf slot assignment FROZEN from R4.
__global__ __launch_bounds__(256, 2) void attn_kernel(
    const short* __restrict__ qb, const short* __restrict__ kb,
    const short* __restrict__ vt, short* __restrict__ ob,
    const float* __restrict__ cosT, const float* __restrict__ sinT) {
  // shorts: K bufs @0,8192 ([64 keys][128 d]); V bufs @16384,24576 ([128 d][64 keys])
  __shared__ alignas(16) short sm[32768];
  const int lane = threadIdx.x & 63, w = threadIdx.x >> 6;
  const int ql = lane & 31, hi = lane >> 5;
  const int qt = blockIdx.x >> 5, bh = blockIdx.x & 31;   // bid = qt*32+bh -> XCD=bh%8
  const int b = bh >> 4, h = bh & 15;
  const int q0w = qt * 128 + w * 32;
  const int qrow = q0w + ql;

  // ---- Q load (B-fragment layout: lane q=ql, d = db*16 + hi*8 + j) + RoPE
  bf16x8 qf[8];
  {
    const short* qp = qb + ((size_t)(b * 2048 + qrow)) * 2048 + h * 128;
#pragma unroll
    for (int db = 0; db < 8; ++db) qf[db] = *(const bf16x8*)(qp + db * 16 + hi * 8);
    const float* cp = cosT + qrow * 32;
    const float* sp = sinT + qrow * 32;
#pragma unroll
    for (int db = 0; db < 2; ++db)
#pragma unroll
      for (int j = 0; j < 8; ++j) {
        int i = db * 16 + hi * 8 + j;
        float x1 = b2f(qf[db][j]), x2 = b2f(qf[db + 2][j]);
        float cv = cp[i], sv = sp[i];
        qf[db][j]     = f2bf(x1 * cv - x2 * sv);
        qf[db + 2][j] = f2bf(x1 * sv + x2 * cv);
      }
  }

  f32x16 o[4];
#pragma unroll
  for (int m4 = 0; m4 < 4; ++m4)
#pragma unroll
    for (int r = 0; r < 16; ++r) o[m4][r] = 0.f;
  float mrun = -3.0e38f, lrun = 0.f;

  auto STAGE = [&](int buf, int kt) {
    // K tile [64 keys][128 d]: linear LDS dest, inverse-swizzled global src.
#pragma unroll
    for (int i = 0; i < 4; ++i) {
      int r = w * 16 + i * 4 + (lane >> 4);
      int cch = lane & 15;
      const short* gp = kb + ((size_t)(b * 2048 + kt * 64 + r)) * 2048 + h * 128 +
                        ((cch ^ (r & 7)) << 3);
      GLDS(gp, sm + buf * 8192 + w * 2048 + i * 512);
    }
    // V^T tile [128 d][64 keys]
#pragma unroll
    for (int i = 0; i < 4; ++i) {
      int rd = w * 32 + i * 8 + (lane >> 3);
      int cch = lane & 7;
      const short* gp = vt + ((size_t)(b * 2048 + h * 128 + rd)) * 2048 + kt * 64 +
                        ((cch ^ (rd & 7)) << 3);
      GLDS(gp, sm + 16384 + buf * 8192 + w * 2048 + i * 512);
    }
  };

  const float cl2 = 0.12752744590518352f;   // (1/sqrt(128)) * log2(e)
  STAGE(0, 0);
  __syncthreads();
  int buf = 0;
  for (int kt = 0; kt < 32; ++kt) {
    if (kt + 1 < 32) STAGE(buf ^ 1, kt + 1);
    const short* Ks = sm + buf * 8192;
    const short* Vs = sm + 16384 + buf * 8192;

    // ---- QK^T (swapped): skt[kb2] = S^T[key block kb2][q], keys in regs
    f32x16 skt[2];
    __builtin_amdgcn_s_setprio(1);
#pragma unroll
    for (int kb2 = 0; kb2 < 2; ++kb2) {
      f32x16 a;
#pragma unroll
      for (int r = 0; r < 16; ++r) a[r] = 0.f;
      int krow = kb2 * 32 + ql;
#pragma unroll
      for (int db = 0; db < 8; ++db) {
        bf16x8 kf = *(const bf16x8*)(Ks + krow * 128 + (((db * 2 + hi) ^ (krow & 7)) << 3));
        a = __builtin_amdgcn_mfma_f32_32x32x16_bf16(kf, qf[db], a, 0, 0, 0);
      }
      skt[kb2] = a;
    }
    __builtin_amdgcn_s_setprio(0);

    // ---- scale into log2 domain (single f32 mul pass)
#pragma unroll
    for (int kb2 = 0; kb2 < 2; ++kb2)
#pragma unroll
      for (int r = 0; r < 16; ++r) skt[kb2][r] *= cl2;

    // ---- row-max via max3 tree (4 chains of 8, then combine, then half-swap)
    float t0, t1, t2, t3;
    t0 = fmaxf(fmaxf(fmaxf(fmaxf(skt[0][0], skt[0][4]), skt[0][8]),
                     fmaxf(skt[0][12], skt[1][0])),
               fmaxf(fmaxf(skt[1][4], skt[1][8]), skt[1][12]));
    t1 = fmaxf(fmaxf(fmaxf(fmaxf(skt[0][1], skt[0][5]), skt[0][9]),
                     fmaxf(skt[0][13], skt[1][1])),
               fmaxf(fmaxf(skt[1][5], skt[1][9]), skt[1][13]));
    t2 = fmaxf(fmaxf(fmaxf(fmaxf(skt[0][2], skt[0][6]), skt[0][10]),
                     fmaxf(skt[0][14], skt[1][2])),
               fmaxf(fmaxf(skt[1][6], skt[1][10]), skt[1][14]));
    t3 = fmaxf(fmaxf(fmaxf(fmaxf(skt[0][3], skt[0][7]), skt[0][11]),
                     fmaxf(skt[0][15], skt[1][3])),
               fmaxf(fmaxf(skt[1][7], skt[1][11]), skt[1][15]));
    float tmax = fmaxf(fmaxf(t0, t1), fmaxf(t2, t3));
    tmax = fmaxf(tmax, __shfl_xor(tmax, 32));

    // ---- defer-max (T13): rescale only when max grew by > 8 (log2 domain)
    if (!__all(tmax <= mrun + 8.0f)) {
      float mn = fmaxf(mrun, tmax);
      float fr = __builtin_amdgcn_exp2f(mrun - mn);
      mrun = mn;
      lrun *= fr;
#pragma unroll
      for (int m4 = 0; m4 < 4; ++m4)
#pragma unroll
        for (int r = 0; r < 16; ++r) o[m4][r] *= fr;
    }
    // ---- exp2 in place + row-sum
    float s0 = 0.f, s1 = 0.f, s2 = 0.f, s3 = 0.f;
#pragma unroll
    for (int kb2 = 0; kb2 < 2; ++kb2)
#pragma unroll
      for (int r = 0; r < 16; r += 4) {
        skt[kb2][r]     = __builtin_amdgcn_exp2f(skt[kb2][r] - mrun);
        skt[kb2][r + 1] = __builtin_amdgcn_exp2f(skt[kb2][r + 1] - mrun);
        skt[kb2][r + 2] = __builtin_amdgcn_exp2f(skt[kb2][r + 2] - mrun);
        skt[kb2][r + 3] = __builtin_amdgcn_exp2f(skt[kb2][r + 3] - mrun);
        s0 += skt[kb2][r];     s1 += skt[kb2][r + 1];
        s2 += skt[kb2][r + 2]; s3 += skt[kb2][r + 3];
      }
    float psum = (s0 + s1) + (s2 + s3);
    psum += __shfl_xor(psum, 32);
    lrun += psum;

    // ---- P -> bf16 P^T B-fragments (slot assignment FROZEN from R4).
    // Lane (ql,hi) holds P[ql][kb2*32 + (r&3)+8*(r>>2)+4*hi].  Target frag
    // pf[ks=2*kb2+half] element (hi,j) = P[ql][key = 32*kb2+16*half+8*hi+j].
    bf16x8 pf[4];
#pragma unroll
    for (int kb2 = 0; kb2 < 2; ++kb2) {
#pragma unroll
      for (int half = 0; half < 2; ++half) {
        unsigned a0 = cvtpk(skt[kb2][half * 8 + 0], skt[kb2][half * 8 + 1]);
        unsigned a1 = cvtpk(skt[kb2][half * 8 + 2], skt[kb2][half * 8 + 3]);
        unsigned b0 = cvtpk(skt[kb2][half * 8 + 4], skt[kb2][half * 8 + 5]);
        unsigned b1 = cvtpk(skt[kb2][half * 8 + 6], skt[kb2][half * 8 + 7]);
        unsigned pa0 = __shfl_xor(a0, 32), pa1 = __shfl_xor(a1, 32);
        unsigned pb0 = __shfl_xor(b0, 32), pb1 = __shfl_xor(b1, 32);
        union { unsigned u[4]; bf16x8 v; } tmp;
        tmp.u[0] = hi ? pb0 : a0;
        tmp.u[1] = hi ? pb1 : a1;
        tmp.u[2] = hi ? b0 : pa0;
        tmp.u[3] = hi ? b1 : pa1;
        pf[kb2 * 2 + half] = tmp.v;
      }
    }

    // ---- PV (swapped): O^T[d][q] += V^T @ P^T
    __builtin_amdgcn_s_setprio(1);
#pragma unroll
    for (int m4 = 0; m4 < 4; ++m4) {
      int rd = m4 * 32 + ql;
#pragma unroll
      for (int ks = 0; ks < 4; ++ks) {
        bf16x8 vf = *(const bf16x8*)(Vs + rd * 64 + (((ks * 2 + hi) ^ (rd & 7)) << 3));
        o[m4] = __builtin_amdgcn_mfma_f32_32x32x16_bf16(vf, pf[ks], o[m4], 0, 0, 0);
      }
    }
    __builtin_amdgcn_s_setprio(0);
    __syncthreads();
    buf ^= 1;
  }

  // ---- epilogue: O^T -> LDS transpose (padded rows) -> coalesced bf16 store
  float il = 1.0f / lrun;
  short* E = sm + w * 4352;                    // [32 q][136 shorts], 16B-aligned rows
#pragma unroll
  for (int m4 = 0; m4 < 4; ++m4)
#pragma unroll
    for (int r = 0; r < 16; r += 2) {
      int d = m4 * 32 + (r & 3) + 8 * (r >> 2) + 4 * hi;
      unsigned pk = cvtpk(o[m4][r] * il, o[m4][r + 1] * il);
      *(unsigned*)(E + ql * 136 + d) = pk;
    }
  asm volatile("s_waitcnt lgkmcnt(0)" ::: "memory");   // wave-private region
#pragma unroll
  for (int it = 0; it < 8; ++it) {
    int row = it * 4 + (lane >> 4);
    int ch = lane & 15;
    bf16x8 v = *(const bf16x8*)(E + row * 136 + ch * 8);
    *(bf16x8*)(ob + ((size_t)(b * 2048 + q0w + row)) * 2048 + h * 128 + ch * 8) = v;
  }
}

// --------------------------------------------------------------- launch ----
extern "C" void kernel_launch(void* const* d_in, const int* in_sizes, int n_in,
                              void* d_out, int out_size, void* d_ws, size_t ws_size,
                              hipStream_t stream) {
  (void)in_sizes; (void)n_in; (void)out_size; (void)ws_size;
  const float* x  = (const float*)d_in[0];
  const int*   pos = (const int*)d_in[1];
  const float* Wq = (const float*)d_in[2];
  const float* Wc = (const float*)d_in[3];
  const float* Wk = (const float*)d_in[4];
  const float* Wv = (const float*)d_in[5];
  const float* Wo = (const float*)d_in[6];

  char* ws = (char*)d_ws;
  short* xb   = (short*)(ws);                 // x bf16            16.78 MB
  short* qb   = (short*)(ws + 16777216);      // q (pre-rope)      16.78 MB
  short* kvb  = (short*)(ws + 33554432);      // latent            4.19 MB
  short* kb   = (short*)(ws + 37748736);      // k                 16.78 MB
  short* vtb  = (short*)(ws + 54525952);      // v transposed      16.78 MB
  short* obuf = (short*)(ws + 71303168);      // attn out          16.78 MB
  short* wqT  = (short*)(ws + 88080384);      // Wq^T              8.39 MB
  short* wcT  = (short*)(ws + 96468992);      // Wc^T              2.10 MB
  short* wkT  = (short*)(ws + 98566144);      // Wk^T              2.10 MB
  short* wvT  = (short*)(ws + 100663296);     // Wv^T              2.10 MB
  short* woT  = (short*)(ws + 102760448);     // Wo^T              8.39 MB
  float* cosT = (float*)(ws + 111149056);     // 0.26 MB
  float* sinT = (float*)(ws + 111411200);     // 0.26 MB

  cast4_kernel<<<8192, 256, 0, stream>>>(x, xb, 2097152);
  transpose_cast_kernel<<<dim3(64, 64), 256, 0, stream>>>(Wq, wqT, 2048, 2048);
  transpose_cast_kernel<<<dim3(16, 64), 256, 0, stream>>>(Wc, wcT, 2048, 512);
  transpose_cast_kernel<<<dim3(64, 16), 256, 0, stream>>>(Wk, wkT, 512, 2048);
  transpose_cast_kernel<<<dim3(64, 16), 256, 0, stream>>>(Wv, wvT, 512, 2048);
  transpose_cast_kernel<<<dim3(64, 64), 256, 0, stream>>>(Wo, woT, 2048, 2048);
  rope_tab_kernel<<<256, 256, 0, stream>>>(pos, cosT, sinT);

  gemm_bt<0><<<dim3(16, 32), 256, 0, stream>>>(xb, wqT, qb, 4096, 2048, 2048);
  gemm_bt<0><<<dim3(4, 32), 256, 0, stream>>>(xb, wcT, kvb, 4096, 512, 2048);
  gemm_bt<0><<<dim3(16, 32), 256, 0, stream>>>(kvb, wkT, kb, 4096, 2048, 512);
  gemm_bt<2><<<dim3(16, 32), 256, 0, stream>>>(kvb, wvT, vtb, 4096, 2048, 512);

  attn_kernel<<<512, 256, 0, stream>>>(qb, kb, vtb, obuf, cosT, sinT);

  gemm_bt<1><<<dim3(16, 32), 256, 0, stream>>>(obuf, woT, (float*)d_out, 4096, 2048, 2048);
}

// Round 7
// 231.998 us; speedup vs baseline: 1.4827x; 1.1723x over previous
//
#include <hip/hip_runtime.h>
#include <math.h>

// LatentCompressedAttention on MI355X (gfx950), bf16-MFMA pipeline.
// B=2, S=2048, D=2048, H=16, Dh=128, LATENT=512, ROPE=64.

typedef __attribute__((ext_vector_type(8))) short bf16x8;    // 8 bf16 in 4 VGPRs
typedef __attribute__((ext_vector_type(4))) float f32x4;
typedef __attribute__((ext_vector_type(16))) float f32x16;

#define GLDS(gp, lp)                                                         \
  __builtin_amdgcn_global_load_lds(                                          \
      (const __attribute__((address_space(1))) void*)(gp),                   \
      (__attribute__((address_space(3))) void*)(lp), 16, 0, 0)

__device__ __forceinline__ short f2bf(float f) {
  unsigned u = __builtin_bit_cast(unsigned, f);
  u += 0x7fffu + ((u >> 16) & 1u);          // RNE
  return (short)(u >> 16);
}
__device__ __forceinline__ float b2f(short x) {
  unsigned u = ((unsigned)(unsigned short)x) << 16;
  return __builtin_bit_cast(float, u);
}
// HW packed f32->bf16 (v_cvt_pk_bf16_f32; lo in low short)
__device__ __forceinline__ unsigned cvtpk(float lo, float hi) {
  unsigned r;
  asm("v_cvt_pk_bf16_f32 %0, %1, %2" : "=v"(r) : "v"(lo), "v"(hi));
  return r;
}

// ---------------------------------------------------------------- casts ----
__global__ void cast4_kernel(const float* __restrict__ x, short* __restrict__ xb, int n4) {
  int i = blockIdx.x * blockDim.x + threadIdx.x;
  if (i < n4) {
    float4 v = ((const float4*)x)[i];
    ushort4 o;
    o.x = (unsigned short)f2bf(v.x);
    o.y = (unsigned short)f2bf(v.y);
    o.z = (unsigned short)f2bf(v.z);
    o.w = (unsigned short)f2bf(v.w);
    ((ushort4*)xb)[i] = o;
  }
}

// W[K][N] fp32 -> Wt[N][K] bf16; gridDim.z selects one of two weight pairs.
__global__ void transpose_cast2_kernel(const float* __restrict__ W0, short* __restrict__ T0,
                                       const float* __restrict__ W1, short* __restrict__ T1,
                                       int K, int N) {
  const float* W = blockIdx.z ? W1 : W0;
  short* Wt = blockIdx.z ? T1 : T0;
  __shared__ float tile[32][33];
  int n0 = blockIdx.x * 32, k0 = blockIdx.y * 32;
  int tx = threadIdx.x & 31, ty = threadIdx.x >> 5;   // ty in 0..7
#pragma unroll
  for (int i = 0; i < 4; ++i)
    tile[ty + i * 8][tx] = W[(size_t)(k0 + ty + i * 8) * N + n0 + tx];
  __syncthreads();
#pragma unroll
  for (int i = 0; i < 4; ++i)
    Wt[(size_t)(n0 + ty + i * 8) * K + k0 + tx] = f2bf(tile[tx][ty + i * 8]);
}

// cos/sin table: [S=2048][32]
__global__ void rope_tab_kernel(const int* __restrict__ pos, float* __restrict__ cosT,
                                float* __restrict__ sinT) {
  int idx = blockIdx.x * 256 + threadIdx.x;
  if (idx < 2048 * 32) {
    int s = idx >> 5, i = idx & 31;
    float p = (float)pos[s];
    float freq = p * powf(10000.0f, -(float)(2 * i) / 64.0f);
    float sv, cv;
    sincosf(freq, &sv, &cv);
    cosT[idx] = cv;
    sinT[idx] = sv;
  }
}

// ----------------------------------------------------------------- GEMM ----
// C = A[M,K] @ Bt[N,K]^T, bf16 in, 128x128 tile, BK=64, 4 waves, T2 swizzle.
// LDS [128][64]-short tiles, rows 128B: naive read = 16-way bank conflict;
// chunk^(row&7) XOR-swizzle (rule 21: linear dest + inv-swz source + swz read)
// makes reads 2-way (free, m136).  BK=64 halves barrier count vs BK=32; the
// accumulation order (kk=0,1 per iter) is identical to two BK=32 iters.
// MODE 0: bf16 row-major. MODE 1: f32 row-major. MODE 2: bf16 transposed-
// within-batch Vt[(b*2048 + n)*2048 + s] (m = b*2048+s).
template <int MODE>
__device__ __forceinline__ void gemm_core(const short* __restrict__ A,
                                          const short* __restrict__ Bt,
                                          void* __restrict__ Cv,
                                          int N, int K, int bm, int bn,
                                          short* sm) {
  const int tid  = threadIdx.x;
  const int lane = tid & 63;
  const int w    = tid >> 6;
  const int col  = lane & 15, g = lane >> 4;
  const int wr = w >> 1, wc = w & 1;

  f32x4 zero4 = {0.f, 0.f, 0.f, 0.f};
  f32x4 acc[4][4];
#pragma unroll
  for (int m = 0; m < 4; ++m)
#pragma unroll
    for (int n = 0; n < 4; ++n) acc[m][n] = zero4;

  const int sr = tid >> 3;            // 0..31: row within a 32-row round
  const int sk = tid & 7;             // 16B chunk within the 128B row

  auto STAGE = [&](int buf, int t) {
#pragma unroll
    for (int i = 0; i < 4; ++i) {
      int r = i * 32 + sr;
      int c = (sk ^ (r & 7)) << 3;    // inverse-swizzled global chunk
      GLDS(A  + (size_t)(bm + r) * K + t * 64 + c,
           sm + buf * 8192 + i * 2048 + w * 512);
      GLDS(Bt + (size_t)(bn + r) * K + t * 64 + c,
           sm + 16384 + buf * 8192 + i * 2048 + w * 512);
    }
  };

  const int nt = K >> 6;
  STAGE(0, 0);
  __syncthreads();
  int buf = 0;
  for (int t = 0; t < nt; ++t) {
    if (t + 1 < nt) STAGE(buf ^ 1, t + 1);     // async prefetch into other buffer
    const short* As = sm + buf * 8192;
    const short* Bs = sm + 16384 + buf * 8192;
#pragma unroll
    for (int kk = 0; kk < 2; ++kk) {
      bf16x8 la[4], lb[4];
#pragma unroll
      for (int m = 0; m < 4; ++m) {
        int row = wr * 64 + m * 16 + col;
        la[m] = *(const bf16x8*)(As + row * 64 + (((kk * 4 + g) ^ (row & 7)) << 3));
      }
#pragma unroll
      for (int n = 0; n < 4; ++n) {
        int row = wc * 64 + n * 16 + col;
        lb[n] = *(const bf16x8*)(Bs + row * 64 + (((kk * 4 + g) ^ (row & 7)) << 3));
      }
#pragma unroll
      for (int m = 0; m < 4; ++m)
#pragma unroll
        for (int n = 0; n < 4; ++n)
          acc[m][n] = __builtin_amdgcn_mfma_f32_16x16x32_bf16(la[m], lb[n], acc[m][n], 0, 0, 0);
    }
    __syncthreads();   // drains vmcnt(0)+lgkmcnt before barrier
    buf ^= 1;
  }

  const int orow0 = bm + wr * 64;
  const int ocol0 = bn + wc * 64;
  if (MODE == 0) {
    short* C = (short*)Cv;
#pragma unroll
    for (int m = 0; m < 4; ++m)
#pragma unroll
      for (int n = 0; n < 4; ++n)
#pragma unroll
        for (int r = 0; r < 4; ++r)
          C[(size_t)(orow0 + m * 16 + g * 4 + r) * N + ocol0 + n * 16 + col] =
              f2bf(acc[m][n][r]);
  } else if (MODE == 1) {
    float* C = (float*)Cv;
#pragma unroll
    for (int m = 0; m < 4; ++m)
#pragma unroll
      for (int n = 0; n < 4; ++n)
#pragma unroll
        for (int r = 0; r < 4; ++r)
          C[(size_t)(orow0 + m * 16 + g * 4 + r) * N + ocol0 + n * 16 + col] =
              acc[m][n][r];
  } else {
    short* C = (short*)Cv;
#pragma unroll
    for (int m = 0; m < 4; ++m)
#pragma unroll
      for (int n = 0; n < 4; ++n) {
        int grow = orow0 + m * 16 + g * 4;
        int bb = grow >> 11, s = grow & 2047;
        int cn = ocol0 + n * 16 + col;
        ushort4 pk;
        pk.x = (unsigned short)f2bf(acc[m][n][0]);
        pk.y = (unsigned short)f2bf(acc[m][n][1]);
        pk.z = (unsigned short)f2bf(acc[m][n][2]);
        pk.w = (unsigned short)f2bf(acc[m][n][3]);
        *(ushort4*)(C + ((size_t)(bb * 2048 + cn)) * 2048 + s) = pk;
      }
  }
}

// Dual-B fused wrappers (block-uniform branch; same K -> aligned barriers).
__global__ __launch_bounds__(256, 2) void gemm_qc(const short* __restrict__ xb,
                                                  const short* __restrict__ wqT,
                                                  const short* __restrict__ wcT,
                                                  short* __restrict__ qb,
                                                  short* __restrict__ kvb) {
  __shared__ alignas(16) short sm[32768];
  int x = blockIdx.x, y = blockIdx.y;
  if (x < 16) gemm_core<0>(xb, wqT, qb, 2048, 2048, y * 128, x * 128, sm);
  else        gemm_core<0>(xb, wcT, kvb, 512, 2048, y * 128, (x - 16) * 128, sm);
}
__global__ __launch_bounds__(256, 2) void gemm_kv(const short* __restrict__ kvb,
                                                  const short* __restrict__ wkT,
                                                  const short* __restrict__ wvT,
                                                  short* __restrict__ kb,
                                                  short* __restrict__ vtb) {
  __shared__ alignas(16) short sm[32768];
  int x = blockIdx.x, y = blockIdx.y;
  if (x < 16) gemm_core<0>(kvb, wkT, kb, 2048, 512, y * 128, x * 128, sm);
  else        gemm_core<2>(kvb, wvT, vtb, 2048, 512, y * 128, (x - 16) * 128, sm);
}
__global__ __launch_bounds__(256, 2) void gemm_wo(const short* __restrict__ obuf,
                                                  const short* __restrict__ woT,
                                                  float* __restrict__ out) {
  __shared__ alignas(16) short sm[32768];
  gemm_core<1>(obuf, woT, out, 2048, 2048, blockIdx.y * 128, blockIdx.x * 128, sm);
}

// ------------------------------------------------------------ attention ----
// R5-VERIFIED kernel, byte-identical (101us, passing).  Swapped-operand 32x32:
//   S^T = K @ Q^T ; O^T = V^T @ P^T ; lane owns one q-row's softmax state.
// XCD-locality 1D grid (bid%8 = bh%8), log2-domain softmax, defer-max THR=8,
// cvt_pk packing, max3 reduce tree.  pf slot assignment FROZEN from R4.
__global__ __launch_bounds__(256, 2) void attn_kernel(
    const short* __restrict__ qb, const short* __restrict__ kb,
    const short* __restrict__ vt, short* __restrict__ ob,
    const float* __restrict__ cosT, const float* __restrict__ sinT) {
  // shorts: K bufs @0,8192 ([64 keys][128 d]); V bufs @16384,24576 ([128 d][64 keys])
  __shared__ alignas(16) short sm[32768];
  const int lane = threadIdx.x & 63, w = threadIdx.x >> 6;
  const int ql = lane & 31, hi = lane >> 5;
  const int qt = blockIdx.x >> 5, bh = blockIdx.x & 31;   // bid = qt*32+bh -> XCD=bh%8
  const int b = bh >> 4, h = bh & 15;
  const int q0w = qt * 128 + w * 32;
  const int qrow = q0w + ql;

  // ---- Q load (B-fragment layout: lane q=ql, d = db*16 + hi*8 + j) + RoPE
  bf16x8 qf[8];
  {
    const short* qp = qb + ((size_t)(b * 2048 + qrow)) * 2048 + h * 128;
#pragma unroll
    for (int db = 0; db < 8; ++db) qf[db] = *(const bf16x8*)(qp + db * 16 + hi * 8);
    const float* cp = cosT + qrow * 32;
    const float* sp = sinT + qrow * 32;
#pragma unroll
    for (int db = 0; db < 2; ++db)
#pragma unroll
      for (int j = 0; j < 8; ++j) {
        int i = db * 16 + hi * 8 + j;
        float x1 = b2f(qf[db][j]), x2 = b2f(qf[db + 2][j]);
        float cv = cp[i], sv = sp[i];
        qf[db][j]     = f2bf(x1 * cv - x2 * sv);
        qf[db + 2][j] = f2bf(x1 * sv + x2 * cv);
      }
  }

  f32x16 o[4];
#pragma unroll
  for (int m4 = 0; m4 < 4; ++m4)
#pragma unroll
    for (int r = 0; r < 16; ++r) o[m4][r] = 0.f;
  float mrun = -3.0e38f, lrun = 0.f;

  auto STAGE = [&](int buf, int kt) {
    // K tile [64 keys][128 d]: linear LDS dest, inverse-swizzled global src.
#pragma unroll
    for (int i = 0; i < 4; ++i) {
      int r = w * 16 + i * 4 + (lane >> 4);
      int cch = lane & 15;
      const short* gp = kb + ((size_t)(b * 2048 + kt * 64 + r)) * 2048 + h * 128 +
                        ((cch ^ (r & 7)) << 3);
      GLDS(gp, sm + buf * 8192 + w * 2048 + i * 512);
    }
    // V^T tile [128 d][64 keys]
#pragma unroll
    for (int i = 0; i < 4; ++i) {
      int rd = w * 32 + i * 8 + (lane >> 3);
      int cch = lane & 7;
      const short* gp = vt + ((size_t)(b * 2048 + h * 128 + rd)) * 2048 + kt * 64 +
                        ((cch ^ (rd & 7)) << 3);
      GLDS(gp, sm + 16384 + buf * 8192 + w * 2048 + i * 512);
    }
  };

  const float cl2 = 0.12752744590518352f;   // (1/sqrt(128)) * log2(e)
  STAGE(0, 0);
  __syncthreads();
  int buf = 0;
  for (int kt = 0; kt < 32; ++kt) {
    if (kt + 1 < 32) STAGE(buf ^ 1, kt + 1);
    const short* Ks = sm + buf * 8192;
    const short* Vs = sm + 16384 + buf * 8192;

    // ---- QK^T (swapped): skt[kb2] = S^T[key block kb2][q], keys in regs
    f32x16 skt[2];
    __builtin_amdgcn_s_setprio(1);
#pragma unroll
    for (int kb2 = 0; kb2 < 2; ++kb2) {
      f32x16 a;
#pragma unroll
      for (int r = 0; r < 16; ++r) a[r] = 0.f;
      int krow = kb2 * 32 + ql;
#pragma unroll
      for (int db = 0; db < 8; ++db) {
        bf16x8 kf = *(const bf16x8*)(Ks + krow * 128 + (((db * 2 + hi) ^ (krow & 7)) << 3));
        a = __builtin_amdgcn_mfma_f32_32x32x16_bf16(kf, qf[db], a, 0, 0, 0);
      }
      skt[kb2] = a;
    }
    __builtin_amdgcn_s_setprio(0);

    // ---- scale into log2 domain (single f32 mul pass)
#pragma unroll
    for (int kb2 = 0; kb2 < 2; ++kb2)
#pragma unroll
      for (int r = 0; r < 16; ++r) skt[kb2][r] *= cl2;

    // ---- row-max via max3 tree (4 chains of 8, then combine, then half-swap)
    float t0, t1, t2, t3;
    t0 = fmaxf(fmaxf(fmaxf(fmaxf(skt[0][0], skt[0][4]), skt[0][8]),
                     fmaxf(skt[0][12], skt[1][0])),
               fmaxf(fmaxf(skt[1][4], skt[1][8]), skt[1][12]));
    t1 = fmaxf(fmaxf(fmaxf(fmaxf(skt[0][1], skt[0][5]), skt[0][9]),
                     fmaxf(skt[0][13], skt[1][1])),
               fmaxf(fmaxf(skt[1][5], skt[1][9]), skt[1][13]));
    t2 = fmaxf(fmaxf(fmaxf(fmaxf(skt[0][2], skt[0][6]), skt[0][10]),
                     fmaxf(skt[0][14], skt[1][2])),
               fmaxf(fmaxf(skt[1][6], skt[1][10]), skt[1][14]));
    t3 = fmaxf(fmaxf(fmaxf(fmaxf(skt[0][3], skt[0][7]), skt[0][11]),
                     fmaxf(skt[0][15], skt[1][3])),
               fmaxf(fmaxf(skt[1][7], skt[1][11]), skt[1][15]));
    float tmax = fmaxf(fmaxf(t0, t1), fmaxf(t2, t3));
    tmax = fmaxf(tmax, __shfl_xor(tmax, 32));

    // ---- defer-max (T13): rescale only when max grew by > 8 (log2 domain)
    if (!__all(tmax <= mrun + 8.0f)) {
      float mn = fmaxf(mrun, tmax);
      float fr = __builtin_amdgcn_exp2f(mrun - mn);
      mrun = mn;
      lrun *= fr;
#pragma unroll
      for (int m4 = 0; m4 < 4; ++m4)
#pragma unroll
        for (int r = 0; r < 16; ++r) o[m4][r] *= fr;
    }
    // ---- exp2 in place + row-sum
    float s0 = 0.f, s1 = 0.f, s2 = 0.f, s3 = 0.f;
#pragma unroll
    for (int kb2 = 0; kb2 < 2; ++kb2)
#pragma unroll
      for (int r = 0; r < 16; r += 4) {
        skt[kb2][r]     = __builtin_amdgcn_exp2f(skt[kb2][r] - mrun);
        skt[kb2][r + 1] = __builtin_amdgcn_exp2f(skt[kb2][r + 1] - mrun);
        skt[kb2][r + 2] = __builtin_amdgcn_exp2f(skt[kb2][r + 2] - mrun);
        skt[kb2][r + 3] = __builtin_amdgcn_exp2f(skt[kb2][r + 3] - mrun);
        s0 += skt[kb2][r];     s1 += skt[kb2][r + 1];
        s2 += skt[kb2][r + 2]; s3 += skt[kb2][r + 3];
      }
    float psum = (s0 + s1) + (s2 + s3);
    psum += __shfl_xor(psum, 32);
    lrun += psum;

    // ---- P -> bf16 P^T B-fragments (slot assignment FROZEN from R4).
    bf16x8 pf[4];
#pragma unroll
    for (int kb2 = 0; kb2 < 2; ++kb2) {
#pragma unroll
      for (int half = 0; half < 2; ++half) {
        unsigned a0 = cvtpk(skt[kb2][half * 8 + 0], skt[kb2][half * 8 + 1]);
        unsigned a1 = cvtpk(skt[kb2][half * 8 + 2], skt[kb2][half * 8 + 3]);
        unsigned b0 = cvtpk(skt[kb2][half * 8 + 4], skt[kb2][half * 8 + 5]);
        unsigned b1 = cvtpk(skt[kb2][half * 8 + 6], skt[kb2][half * 8 + 7]);
        unsigned pa0 = __shfl_xor(a0, 32), pa1 = __shfl_xor(a1, 32);
        unsigned pb0 = __shfl_xor(b0, 32), pb1 = __shfl_xor(b1, 32);
        union { unsigned u[4]; bf16x8 v; } tmp;
        tmp.u[0] = hi ? pb0 : a0;
        tmp.u[1] = hi ? pb1 : a1;
        tmp.u[2] = hi ? b0 : pa0;
        tmp.u[3] = hi ? b1 : pa1;
        pf[kb2 * 2 + half] = tmp.v;
      }
    }

    // ---- PV (swapped): O^T[d][q] += V^T @ P^T
    __builtin_amdgcn_s_setprio(1);
#pragma unroll
    for (int m4 = 0; m4 < 4; ++m4) {
      int rd = m4 * 32 + ql;
#pragma unroll
      for (int ks = 0; ks < 4; ++ks) {
        bf16x8 vf = *(const bf16x8*)(Vs + rd * 64 + (((ks * 2 + hi) ^ (rd & 7)) << 3));
        o[m4] = __builtin_amdgcn_mfma_f32_32x32x16_bf16(vf, pf[ks], o[m4], 0, 0, 0);
      }
    }
    __builtin_amdgcn_s_setprio(0);
    __syncthreads();
    buf ^= 1;
  }

  // ---- epilogue: O^T -> LDS transpose (padded rows) -> coalesced bf16 store
  float il = 1.0f / lrun;
  short* E = sm + w * 4352;                    // [32 q][136 shorts], 16B-aligned rows
#pragma unroll
  for (int m4 = 0; m4 < 4; ++m4)
#pragma unroll
    for (int r = 0; r < 16; r += 2) {
      int d = m4 * 32 + (r & 3) + 8 * (r >> 2) + 4 * hi;
      unsigned pk = cvtpk(o[m4][r] * il, o[m4][r + 1] * il);
      *(unsigned*)(E + ql * 136 + d) = pk;
    }
  asm volatile("s_waitcnt lgkmcnt(0)" ::: "memory");   // wave-private region
#pragma unroll
  for (int it = 0; it < 8; ++it) {
    int row = it * 4 + (lane >> 4);
    int ch = lane & 15;
    bf16x8 v = *(const bf16x8*)(E + row * 136 + ch * 8);
    *(bf16x8*)(ob + ((size_t)(b * 2048 + q0w + row)) * 2048 + h * 128 + ch * 8) = v;
  }
}

// --------------------------------------------------------------- launch ----
extern "C" void kernel_launch(void* const* d_in, const int* in_sizes, int n_in,
                              void* d_out, int out_size, void* d_ws, size_t ws_size,
                              hipStream_t stream) {
  (void)in_sizes; (void)n_in; (void)out_size; (void)ws_size;
  const float* x  = (const float*)d_in[0];
  const int*   pos = (const int*)d_in[1];
  const float* Wq = (const float*)d_in[2];
  const float* Wc = (const float*)d_in[3];
  const float* Wk = (const float*)d_in[4];
  const float* Wv = (const float*)d_in[5];
  const float* Wo = (const float*)d_in[6];

  char* ws = (char*)d_ws;
  short* xb   = (short*)(ws);                 // x bf16            16.78 MB
  short* qb   = (short*)(ws + 16777216);      // q (pre-rope)      16.78 MB
  short* kvb  = (short*)(ws + 33554432);      // latent            4.19 MB
  short* kb   = (short*)(ws + 37748736);      // k                 16.78 MB
  short* vtb  = (short*)(ws + 54525952);      // v transposed      16.78 MB
  short* obuf = (short*)(ws + 71303168);      // attn out          16.78 MB
  short* wqT  = (short*)(ws + 88080384);      // Wq^T              8.39 MB
  short* wcT  = (short*)(ws + 96468992);      // Wc^T              2.10 MB
  short* wkT  = (short*)(ws + 98566144);      // Wk^T              2.10 MB
  short* wvT  = (short*)(ws + 100663296);     // Wv^T              2.10 MB
  short* woT  = (short*)(ws + 102760448);     // Wo^T              8.39 MB
  float* cosT = (float*)(ws + 111149056);     // 0.26 MB
  float* sinT = (float*)(ws + 111411200);     // 0.26 MB

  cast4_kernel<<<8192, 256, 0, stream>>>(x, xb, 2097152);
  transpose_cast2_kernel<<<dim3(64, 64, 2), 256, 0, stream>>>(Wq, wqT, Wo, woT, 2048, 2048);
  transpose_cast2_kernel<<<dim3(16, 64, 1), 256, 0, stream>>>(Wc, wcT, Wc, wcT, 2048, 512);
  transpose_cast2_kernel<<<dim3(64, 16, 2), 256, 0, stream>>>(Wk, wkT, Wv, wvT, 512, 2048);
  rope_tab_kernel<<<256, 256, 0, stream>>>(pos, cosT, sinT);

  gemm_qc<<<dim3(20, 32), 256, 0, stream>>>(xb, wqT, wcT, qb, kvb);
  gemm_kv<<<dim3(32, 32), 256, 0, stream>>>(kvb, wkT, wvT, kb, vtb);

  attn_kernel<<<512, 256, 0, stream>>>(qb, kb, vtb, obuf, cosT, sinT);

  gemm_wo<<<dim3(16, 32), 256, 0, stream>>>(obuf, woT, (float*)d_out);
}